// Round 3
// baseline (1337.364 us; speedup 1.0000x reference)
//
#include <hip/hip_runtime.h>

typedef unsigned int u32;
typedef unsigned short u16;
typedef short short8 __attribute__((ext_vector_type(8)));   // 8 x bf16 (4 VGPRs)
typedef float floatx4 __attribute__((ext_vector_type(4)));  // MFMA accumulator

static __device__ __forceinline__ u32 f2bf(float f) {
  u32 u = __float_as_uint(f);
  return (u + 0x7fffu + ((u >> 16) & 1u)) >> 16;  // RNE bf16 bits
}
// HW packed f32->bf16 (RNE), 1 instr replaces ~9 ALU ops of f2bf|f2bf<<16
static __device__ __forceinline__ u32 cvtpk(float lo, float hi) {
  u32 r;
  asm("v_cvt_pk_bf16_f32 %0, %1, %2" : "=v"(r) : "v"(lo), "v"(hi));
  return r;
}

// ---------------------------------------------------------------------------
// MFMA conventions (verified): for mfma_f32_16x16x32_bf16(A,B,C):
//   A-frag: lane holds A[m = lane&15][k = quad*8+j], j=0..7 (one 16B load)
//   B-frag: lane holds B[k = quad*8+j][n = lane&15]  (value = W[n][k])
//   C/D   : col(n) = lane&15, row(m) = quad*4 + reg
// conv1: A=weights(m=cout), B=x0T(n=p), K=64 (k=tap*8+cin; tap>4,cin>5 zero)
// conv2: A=x1t(m=p),  B=weights(n=o), K=96 (k=tap*16+c; tap>4 zero)
// fc:    A=sF frag,   B=fcwsw(n=outch), K=4096 (feat=o*128+p; p>119 zero)
//
// Round-r structure (r=0..3): fc K-dim split by p-pairs pt in {2r,2r+1}.
// conv2 output of round r lives in LDS sF (32 KiB, frag order, swizzled).
// conv1 recomputed per round over window pt' = 2r-1 .. 2r+2 (clamped 0..7);
// x1 window rows: lrow = globalrow - 32r + 16, rows 0..65, reads 16..52.
// Zero-trim: only lrows {16,17}@r=0 and {42..52}@r=3 are read-never-written.
// Pipelining (this round): fc B-chunks o=0..7 prefetched to regs at conv
// start (drained by the pre-fc barrier); next tile's ea loads issued at
// round-3 conv start, sX0(t+1) written between barrier A3 and fc(3), so
// B3 doubles as the stage barrier (8 barriers/tile, stage latency hidden).
// LDS: sX0 34816 + sX1 12672 + sF 32768 = 80256 B -> 2 blocks/CU.
// ---------------------------------------------------------------------------

#define X0_ROWS 136    // u16[8] granules per node; row r = position r-2
#define X1W_ROWS 66    // sliding window rows (local)
#define X1W_LDA 24     // u16 per row (48 B, 16B-aligned rows)

__global__ __launch_bounds__(256, 2) void k_convfc(
    const float* __restrict__ ea,
    const u32* __restrict__ w1sw, const float* __restrict__ b1,
    const u32* __restrict__ w2sw, const float* __restrict__ b2,
    const u32* __restrict__ fcwsw, const float* __restrict__ fcb,
    float* __restrict__ xfc, int n, int ntiles)
{
  __shared__ __align__(16) u16 sX0[16][X0_ROWS * 8];        // 34816 B, all 16 nodes
  __shared__ __align__(16) u16 sX1[4][X1W_ROWS * X1W_LDA];  // 12672 B, per-wave window
  __shared__ __align__(16) u16 sF[32 * 64 * 8];             // 32768 B, fc A-frags

  const int t = threadIdx.x, lane = t & 63, wv = t >> 6;
  const int quad = lane >> 4, lr = lane & 15;

  // zero x0 once: halo rows (0,1) and pad rows (>=122) stay zero forever
  for (int i = t; i < 16 * X0_ROWS * 4; i += 256) ((u32*)sX0)[i] = 0;

  // weights into registers
  short8 w1f[2], w2f[2][3];
#pragma unroll
  for (int kb = 0; kb < 2; ++kb) w1f[kb] = ((const short8*)w1sw)[kb * 64 + lane];
#pragma unroll
  for (int ot = 0; ot < 2; ++ot)
#pragma unroll
    for (int kb = 0; kb < 3; ++kb)
      w2f[ot][kb] = ((const short8*)w2sw)[(ot * 3 + kb) * 64 + lane];

  float b1r[4];
#pragma unroll
  for (int r = 0; r < 4; ++r) b1r[r] = b1[quad * 4 + r];
  const float bv20 = b2[lr], bv21 = b2[16 + lr];

  // fc setup
  const int c0 = wv * 16 + lr, c1 = (wv + 4) * 16 + lr;
  const float bv0 = fcb[c0], bv1 = fcb[c1];
  const short8* bw = (const short8*)fcwsw;
  const short8* b0p = bw + ((size_t)wv * 128) * 64 + lane;
  const short8* b1p = bw + ((size_t)(wv + 4) * 128) * 64 + lane;
  const int j2base = wv * 4;

  // ---- one conv round (r folds to constants under #pragma unroll) ----------
  auto conv_round = [&](int r) {
    u16* x1 = sX1[wv];
    // per-round zero-trim (wave-private buffer, no barrier needed)
    if (r == 0) {
      if (lane < 24) ((u32*)(x1 + 16 * X1W_LDA))[lane] = 0;   // lrows 16,17
    } else if (r == 3) {
      u32* z = (u32*)(x1 + 42 * X1W_LDA);                     // lrows 42..52
#pragma unroll
      for (int i2 = 0; i2 < 3; ++i2) {
        int i = lane + i2 * 64;
        if (i < 132) z[i] = 0;
      }
    }
    const int tq = quad >> 1, cq = (quad & 1) * 8;
#pragma unroll
    for (int jj = 0; jj < 4; ++jj) {
      const int j2 = j2base + jj;
      const u16* x0n = sX0[j2];
      // ---- conv1 over window pt' = 2r-1 .. 2r+2 (statically clamped) ----
#pragma unroll
      for (int q4 = 0; q4 < 4; ++q4) {
        const int ptp = 2 * r - 1 + q4;
        if (ptp >= 0 && ptp <= 7) {       // folds at compile time
          const int row0 = ptp * 16 + lr;
          short8 bx0 = *(const short8*)&x0n[(row0 + quad) * 8];       // taps 0..3
          short8 bx1 = *(const short8*)&x0n[(row0 + 4 + quad) * 8];   // taps 4..7
          floatx4 a1 = {b1r[0], b1r[1], b1r[2], b1r[3]};
          a1 = __builtin_amdgcn_mfma_f32_16x16x32_bf16(w1f[0], bx0, a1, 0, 0, 0);
          a1 = __builtin_amdgcn_mfma_f32_16x16x32_bf16(w1f[1], bx1, a1, 0, 0, 0);
          if (ptp < 7 || lr < 8) {        // only valid positions p<120
            const int lrow = row0 + 18 - 32 * r;   // globalrow+2 -> window
            u32 lo = cvtpk(fmaxf(a1[0], 0.0f), fmaxf(a1[1], 0.0f));
            u32 hi = cvtpk(fmaxf(a1[2], 0.0f), fmaxf(a1[3], 0.0f));
            *(uint2*)&x1[lrow * X1W_LDA + quad * 4] = make_uint2(lo, hi);
          }
        }
      }
      // ---- conv2 for pt in {2r, 2r+1} -> sF (LDS, frag order, swizzled) ----
#pragma unroll
      for (int ptl = 0; ptl < 2; ++ptl) {
        const int lrow0 = ptl * 16 + lr + 16;
        short8 ax0 = *(const short8*)&x1[(lrow0 + tq) * X1W_LDA + cq];       // taps 0,1
        short8 ax1 = *(const short8*)&x1[(lrow0 + 2 + tq) * X1W_LDA + cq];   // taps 2,3
        short8 ax2 = *(const short8*)&x1[(lrow0 + 4 + tq) * X1W_LDA + cq];   // taps 4,5(zeroW)
#pragma unroll
        for (int ot = 0; ot < 2; ++ot) {
          const float bb = ot ? bv21 : bv20;
          floatx4 a2 = {bb, bb, bb, bb};
          a2 = __builtin_amdgcn_mfma_f32_16x16x32_bf16(ax0, w2f[ot][0], a2, 0, 0, 0);
          a2 = __builtin_amdgcn_mfma_f32_16x16x32_bf16(ax1, w2f[ot][1], a2, 0, 0, 0);
          a2 = __builtin_amdgcn_mfma_f32_16x16x32_bf16(ax2, w2f[ot][2], a2, 0, 0, 0);
          u32 lo = cvtpk(fmaxf(a2[0], 0.0f), fmaxf(a2[1], 0.0f));
          u32 hi = cvtpk(fmaxf(a2[2], 0.0f), fmaxf(a2[3], 0.0f));
          // value (node j2, o=ot*16+lr, p=pt*16+quad*4+rr)
          const int o = ot * 16 + lr;
          const int s = (ptl * 2 + tq) * 16 + j2;
          const int G = o * 64 + (s ^ (o & 7));   // bank swizzle
          *(uint2*)&sF[G * 8 + (quad & 1) * 4] = make_uint2(lo, hi);
        }
      }
    }  // jj
  };

  __syncthreads();  // sX0 zero-init visible

  // ---- stage first tile directly -----------------------------------------
  int tile = blockIdx.x;
  if (tile < ntiles) {
    const long node0 = (long)tile * 16;
#pragma unroll
    for (int it = 0; it < 8; ++it) {
      int idx = t + it * 256;                 // 0..2047
      int nd = idx >> 7, p = idx & 127;
      if (p < 120) {
        long gn = node0 + nd;
        float v0 = 0.f, v1 = 0.f, v2 = 0.f, v3 = 0.f, v4 = 0.f, v5 = 0.f;
        if (gn < n) {
          const float* base = ea + (size_t)gn * 720 + p;
          v0 = base[0];   v1 = base[120]; v2 = base[240];
          v3 = base[360]; v4 = base[480]; v5 = base[600];
        }
        u32 w0 = cvtpk(v0, v1), w1 = cvtpk(v2, v3), w2 = cvtpk(v4, v5);
        *(uint4*)&sX0[nd][(p + 2) * 8] = make_uint4(w0, w1, w2, 0u);
      }
    }
  }
  __syncthreads();

  for (; tile < ntiles; tile += gridDim.x) {
    const long node0 = (long)tile * 16;
    floatx4 acc0 = {bv0, bv0, bv0, bv0};
    floatx4 acc1 = {bv1, bv1, bv1, bv1};

    // ---- rounds 0..2: fc B-prefetch (o<8) overlapped with conv -----------
#pragma unroll
    for (int r = 0; r < 3; ++r) {
      short8 pb0[8], pb1[8];
#pragma unroll
      for (int o = 0; o < 8; ++o) {
        const int ks = o * 4 + r;
        pb0[o] = b0p[(size_t)ks * 64];
        pb1[o] = b1p[(size_t)ks * 64];
      }
      conv_round(r);
      __syncthreads();  // sF complete for this round (drains prefetch too)
#pragma unroll
      for (int o = 0; o < 8; ++o) {
        short8 a = *(const short8*)&sF[(o * 64 + (lane ^ (o & 7))) * 8];
        acc0 = __builtin_amdgcn_mfma_f32_16x16x32_bf16(a, pb0[o], acc0, 0, 0, 0);
        acc1 = __builtin_amdgcn_mfma_f32_16x16x32_bf16(a, pb1[o], acc1, 0, 0, 0);
      }
#pragma unroll 8
      for (int o = 8; o < 32; ++o) {
        short8 a = *(const short8*)&sF[(o * 64 + (lane ^ (o & 7))) * 8];
        const int ks = o * 4 + r;
        short8 bb0 = b0p[(size_t)ks * 64];
        short8 bb1 = b1p[(size_t)ks * 64];
        acc0 = __builtin_amdgcn_mfma_f32_16x16x32_bf16(a, bb0, acc0, 0, 0, 0);
        acc1 = __builtin_amdgcn_mfma_f32_16x16x32_bf16(a, bb1, acc1, 0, 0, 0);
      }
      __syncthreads();  // fc reads done before next round overwrites sF
    }  // r = 0..2

    // ---- round 3: next-tile ea prefetch overlapped with conv -------------
    const long ntnode0 = ((long)tile + gridDim.x) * 16;
    float ev[8][6];
#pragma unroll
    for (int it = 0; it < 8; ++it) {
      int idx = t + it * 256;
      int nd = idx >> 7, p = idx & 127;
#pragma unroll
      for (int c6 = 0; c6 < 6; ++c6) ev[it][c6] = 0.0f;
      if (p < 120) {
        long gn = ntnode0 + nd;
        if (gn < n) {
          const float* base = ea + (size_t)gn * 720 + p;
          ev[it][0] = base[0];   ev[it][1] = base[120]; ev[it][2] = base[240];
          ev[it][3] = base[360]; ev[it][4] = base[480]; ev[it][5] = base[600];
        }
      }
    }
    conv_round(3);
    __syncthreads();  // A3: all conv reads of sX0(t) + sF(3) writes complete

    // write next tile's sX0 (visible after the post-fc barrier B3)
#pragma unroll
    for (int it = 0; it < 8; ++it) {
      int idx = t + it * 256;
      int nd = idx >> 7, p = idx & 127;
      if (p < 120) {
        u32 w0 = cvtpk(ev[it][0], ev[it][1]);
        u32 w1 = cvtpk(ev[it][2], ev[it][3]);
        u32 w2 = cvtpk(ev[it][4], ev[it][5]);
        *(uint4*)&sX0[nd][(p + 2) * 8] = make_uint4(w0, w1, w2, 0u);
      }
    }

    // fc round 3 (all inline)
#pragma unroll 8
    for (int o = 0; o < 32; ++o) {
      short8 a = *(const short8*)&sF[(o * 64 + (lane ^ (o & 7))) * 8];
      const int ks = o * 4 + 3;
      short8 bb0 = b0p[(size_t)ks * 64];
      short8 bb1 = b1p[(size_t)ks * 64];
      acc0 = __builtin_amdgcn_mfma_f32_16x16x32_bf16(a, bb0, acc0, 0, 0, 0);
      acc1 = __builtin_amdgcn_mfma_f32_16x16x32_bf16(a, bb1, acc1, 0, 0, 0);
    }

#pragma unroll
    for (int rr = 0; rr < 4; ++rr) {
      long node = node0 + quad * 4 + rr;
      if (node < n) {
        xfc[node * 128 + c0] = acc0[rr];
        xfc[node * 128 + c1] = acc1[rr];
      }
    }
    __syncthreads();  // B3: sX0(t+1) + all sF(3) reads ordered before next conv
  }
}

// ---------------------------------------------------------------------------
// Merged prep: fcwsw / g1wsw / g2wsw / w1sw / w2sw swizzles + dinv=1 + pooled=0
// ---------------------------------------------------------------------------
__global__ void k_prep(const float* __restrict__ fcw, const float* __restrict__ g1w,
                       const float* __restrict__ g2w, const float* __restrict__ w1,
                       const float* __restrict__ w2,
                       uint4* __restrict__ fcwsw, uint4* __restrict__ g1wsw,
                       uint4* __restrict__ g2wsw, uint4* __restrict__ w1sw,
                       uint4* __restrict__ w2sw,
                       float* __restrict__ dinv, float* __restrict__ pooled, int n)
{
  int gid = blockIdx.x * 256 + threadIdx.x;
  if (gid < 65536) {  // fcwsw: entry = (nt*128+ks)*64+lane, feat k = o*128+p
    int e = gid, lane = e & 63, t2 = e >> 6, ks = t2 & 127, nt = t2 >> 7;
    int col = nt * 16 + (lane & 15);
    int k0 = ks * 32 + ((lane >> 4) & 3) * 8;
    u32 pk[4];
#pragma unroll
    for (int h = 0; h < 4; ++h) {
      u32 v01[2];
#pragma unroll
      for (int g = 0; g < 2; ++g) {
        int k = k0 + h * 2 + g;
        int o = k >> 7, p = k & 127;
        float v = (p < 120) ? fcw[(size_t)col * 3840 + o * 120 + p] : 0.0f;
        v01[g] = f2bf(v);
      }
      pk[h] = v01[0] | (v01[1] << 16);
    }
    fcwsw[e] = make_uint4(pk[0], pk[1], pk[2], pk[3]);
    return;
  }
  gid -= 65536;
  if (gid < 4096) {  // g1wsw / g2wsw: entry = (nt*4+kb)*64+lane
    const float* gw = (gid < 2048) ? g1w : g2w;
    uint4* out = (gid < 2048) ? g1wsw : g2wsw;
    int e = gid & 2047, lane = e & 63;
    int col = (e >> 8) * 16 + (lane & 15);            // nt = e>>8 (t2>>2)
    int k0 = ((e >> 6) & 3) * 32 + ((lane >> 4) & 3) * 8;
    u32 pk[4];
#pragma unroll
    for (int h = 0; h < 4; ++h)
      pk[h] = f2bf(gw[(size_t)col * 128 + k0 + h * 2]) |
              (f2bf(gw[(size_t)col * 128 + k0 + h * 2 + 1]) << 16);
    out[e] = make_uint4(pk[0], pk[1], pk[2], pk[3]);
    return;
  }
  gid -= 4096;
  if (gid < 128) {  // w1sw: entry = kb*64+lane; k = tap*8+cin
    int e = gid, lane = e & 63, kb = e >> 6, cout = lane & 15;
    int k0 = kb * 32 + ((lane >> 4) & 3) * 8;
    u32 pk[4];
#pragma unroll
    for (int h = 0; h < 4; ++h) {
      u32 v01[2];
#pragma unroll
      for (int g = 0; g < 2; ++g) {
        int k = k0 + h * 2 + g, tap = k >> 3, cin = k & 7;
        float v = (tap < 5 && cin < 6) ? w1[cout * 30 + cin * 5 + tap] : 0.0f;
        v01[g] = f2bf(v);
      }
      pk[h] = v01[0] | (v01[1] << 16);
    }
    w1sw[e] = make_uint4(pk[0], pk[1], pk[2], pk[3]);
    return;
  }
  gid -= 128;
  if (gid < 384) {  // w2sw: entry = (ot*3+kb)*64+lane; k = tap*16+c
    int e = gid, lane = e & 63, t2 = e >> 6;
    int kb = t2 % 3, ot = t2 / 3;
    int o = ot * 16 + (lane & 15);
    int k0 = kb * 32 + ((lane >> 4) & 3) * 8;
    u32 pk[4];
#pragma unroll
    for (int h = 0; h < 4; ++h) {
      u32 v01[2];
#pragma unroll
      for (int g = 0; g < 2; ++g) {
        int k = k0 + h * 2 + g, tap = k >> 4, c = k & 15;
        float v = (tap < 5) ? w2[o * 80 + c * 5 + tap] : 0.0f;
        v01[g] = f2bf(v);
      }
      pk[h] = v01[0] | (v01[1] << 16);
    }
    w2sw[e] = make_uint4(pk[0], pk[1], pk[2], pk[3]);
    return;
  }
  gid -= 384;
  if (gid < n) { dinv[gid] = 1.0f; return; }
  gid -= n;
  if (gid < 8192) pooled[gid] = 0.0f;
}

// ---------------------------------------------------------------------------
// GCN dense layer via MFMA, fused self-loop + bias:
//   H[i][o] = sum_k act(X[i][k]) * W[o][k]
//   Out[i][o] = bias[o] + dinv[i]^2 * H[i][o]
// ---------------------------------------------------------------------------
__global__ __launch_bounds__(256) void k_gcn_gemm(
    const float* __restrict__ X, const u32* __restrict__ wsw,
    const float* __restrict__ bias, const float* __restrict__ dinv,
    float* __restrict__ H, float* __restrict__ Out, int n, int relu)
{
  __shared__ __align__(16) u16 sA[16 * 136];
  __shared__ float sDi[16];
  const int t = threadIdx.x;
  const long node0 = (long)blockIdx.x * 16;
  {
    int nd = t >> 4, k0 = (t & 15) * 8;
    long node = node0 + nd;
    float v[8];
    if (node < n) {
      float4 f0 = *(const float4*)&X[node * 128 + k0];
      float4 f1 = *(const float4*)&X[node * 128 + k0 + 4];
      v[0]=f0.x; v[1]=f0.y; v[2]=f0.z; v[3]=f0.w; v[4]=f1.x; v[5]=f1.y; v[6]=f1.z; v[7]=f1.w;
      if (relu) {
#pragma unroll
        for (int i = 0; i < 8; ++i) v[i] = fmaxf(v[i], 0.0f);
      }
    } else {
#pragma unroll
      for (int i = 0; i < 8; ++i) v[i] = 0.0f;
    }
    u32 pk[4];
#pragma unroll
    for (int h = 0; h < 4; ++h) pk[h] = cvtpk(v[2*h], v[2*h+1]);
    *(uint4*)&sA[nd * 136 + k0] = make_uint4(pk[0], pk[1], pk[2], pk[3]);
    if (t < 16) sDi[t] = (node0 + t < n) ? dinv[node0 + t] : 0.0f;
  }
  __syncthreads();
  const int lane = t & 63, wv = t >> 6, quad = lane >> 4, lr = lane & 15;
  short8 af[4];
#pragma unroll
  for (int kb = 0; kb < 4; ++kb)
    af[kb] = *(const short8*)&sA[lr * 136 + kb * 32 + quad * 8];
#pragma unroll
  for (int h = 0; h < 2; ++h) {
    const int nt = wv + h * 4;
    const short8* bp = ((const short8*)wsw) + (nt * 4) * 64 + lane;
    floatx4 acc = {0.0f, 0.0f, 0.0f, 0.0f};
#pragma unroll
    for (int kb = 0; kb < 4; ++kb)
      acc = __builtin_amdgcn_mfma_f32_16x16x32_bf16(af[kb], bp[kb * 64], acc, 0, 0, 0);
    const int col = nt * 16 + lr;
    const float bcol = bias[col];
#pragma unroll
    for (int r = 0; r < 4; ++r) {
      long node = node0 + quad * 4 + r;
      if (node < n) {
        float hv = acc[r];
        float di = sDi[quad * 4 + r];
        H[node * 128 + col] = hv;
        Out[node * 128 + col] = bcol + di * di * hv;
      }
    }
  }
}

// One wave per real edge; symmetric-norm message scatter (self-loops pre-seeded).
__global__ void k_scatter(const float* __restrict__ Hs, float* __restrict__ Out,
                          const int* __restrict__ src, const int* __restrict__ dst,
                          const float* __restrict__ dinv, int n)
{
  const int gid = blockIdx.x * blockDim.x + threadIdx.x;
  const int e = gid >> 6;
  const int lane = gid & 63;
  if (e >= n) return;
  const int s = src[e], d = dst[e];
  const float nrm = dinv[s] * dinv[d];
  const float2 v = *(const float2*)(Hs + (size_t)s * 128 + lane * 2);
  float* o = Out + (size_t)d * 128 + lane * 2;
  unsafeAtomicAdd(o, v.x * nrm);
  unsafeAtomicAdd(o + 1, v.y * nrm);
}

__global__ void k_deg(float* dinv, const int* __restrict__ dst, int n) {
  int i = blockIdx.x * 256 + threadIdx.x; if (i < n) unsafeAtomicAdd(&dinv[dst[i]], 1.0f);
}
__global__ void k_rsqrt(float* p, int n) {
  int i = blockIdx.x * 256 + threadIdx.x; if (i < n) p[i] = rsqrtf(p[i]);
}

// LDS-staged pooling: pooled[batch[src[e]]] += X[e]
__global__ __launch_bounds__(256) void k_pool(const float* __restrict__ X,
    const int* __restrict__ src, const int* __restrict__ batch,
    float* __restrict__ pooled, int n)
{
  __shared__ float sAcc[64 * 128];
  for (int i = threadIdx.x; i < 8192; i += 256) sAcc[i] = 0.0f;
  __syncthreads();
  const int c = threadIdx.x & 127, half = threadIdx.x >> 7;
  for (int e = blockIdx.x * 2 + half; e < n; e += gridDim.x * 2) {
    int g = batch[src[e]];
    atomicAdd(&sAcc[g * 128 + c], X[(size_t)e * 128 + c]);
  }
  __syncthreads();
  for (int i = threadIdx.x; i < 8192; i += 256) unsafeAtomicAdd(&pooled[i], sAcc[i]);
}

// Final MLP head: relu(pooled @ fc1.T + b1) @ fc2.T + b2  (one block per graph)
__global__ __launch_bounds__(256) void k_mlp(const float* __restrict__ pooled,
    const float* __restrict__ f1w, const float* __restrict__ f1b,
    const float* __restrict__ f2w, const float* __restrict__ f2b,
    float* __restrict__ out)
{
  const int g = blockIdx.x, t = threadIdx.x;
  __shared__ float sP[128];
  __shared__ float sY[256];
  if (t < 128) sP[t] = pooled[g * 128 + t];
  __syncthreads();
  {
    const float* w = f1w + (size_t)t * 128;
    float a = f1b[t];
    for (int k = 0; k < 128; k += 4) {
      float4 w4 = *(const float4*)(w + k);
      a = fmaf(w4.x, sP[k], fmaf(w4.y, sP[k+1], fmaf(w4.z, sP[k+2], fmaf(w4.w, sP[k+3], a))));
    }
    sY[t] = fmaxf(a, 0.0f);
  }
  __syncthreads();
  if (t < 128) {
    const float* w = f2w + (size_t)t * 256;
    float a = f2b[t];
    for (int k = 0; k < 256; k += 4) {
      float4 w4 = *(const float4*)(w + k);
      a = fmaf(w4.x, sY[k], fmaf(w4.y, sY[k+1], fmaf(w4.z, sY[k+2], fmaf(w4.w, sY[k+3], a))));
    }
    out[g * 128 + t] = a;
  }
}

extern "C" void kernel_launch(void* const* d_in, const int* in_sizes, int n_in,
                              void* d_out, int out_size, void* d_ws, size_t ws_size,
                              hipStream_t stream) {
  const float* ea  = (const float*)d_in[0];
  const int* eidx  = (const int*)d_in[1];
  const int* batch = (const int*)d_in[2];
  const float* w1  = (const float*)d_in[4];
  const float* b1  = (const float*)d_in[5];
  const float* w2  = (const float*)d_in[6];
  const float* b2  = (const float*)d_in[7];
  const float* fcw = (const float*)d_in[8];
  const float* fcb = (const float*)d_in[9];
  const float* g1w = (const float*)d_in[10];
  const float* g1b = (const float*)d_in[11];
  const float* g2w = (const float*)d_in[12];
  const float* g2b = (const float*)d_in[13];
  const float* f1w = (const float*)d_in[14];
  const float* f1b = (const float*)d_in[15];
  const float* f2w = (const float*)d_in[16];
  const float* f2b = (const float*)d_in[17];

  const int n = in_sizes[0] / 720;   // 100000
  const int* src = eidx;             // edge_index[0]
  const int* dst = eidx + n;         // edge_index[1]

  // workspace layout (~155.3 MB; conv2->fc slab lives in LDS)
  float* A      = (float*)d_ws;                   // [n,128]
  float* B      = A + (size_t)n * 128;            // [n,128]
  float* C      = B + (size_t)n * 128;            // [n,128]
  float* dinv   = C + (size_t)n * 128;            // [n]
  float* pooled = dinv + n;                       // [64,128]
  u32*   fcwsw  = (u32*)(pooled + 64 * 128);      // 65536 uint4 = 1 MB
  u32*   g1wsw  = fcwsw + 65536 * 4;              // 2048 uint4
  u32*   g2wsw  = g1wsw + 2048 * 4;               // 2048 uint4
  u32*   w1sw   = g2wsw + 2048 * 4;               // 128 uint4
  u32*   w2sw   = w1sw + 128 * 4;                 // 384 uint4

  const int nb_n = (n + 255) / 256;
  const int ntiles = (n + 15) / 16;
  const int prep_total = 65536 + 2048 + 2048 + 128 + 384 + n + 8192;
  k_prep<<<(prep_total + 255) / 256, 256, 0, stream>>>(
      fcw, g1w, g2w, w1, w2, (uint4*)fcwsw, (uint4*)g1wsw, (uint4*)g2wsw,
      (uint4*)w1sw, (uint4*)w2sw, dinv, pooled, n);
  k_deg<<<nb_n, 256, 0, stream>>>(dinv, dst, n);
  k_rsqrt<<<nb_n, 256, 0, stream>>>(dinv, n);

  // 80.3 KiB LDS/block -> 2 blocks/CU; 512 blocks = 2 per CU exactly
  k_convfc<<<512, 256, 0, stream>>>(ea, w1sw, b1, w2sw, b2, fcwsw, fcb, A, n, ntiles);

  // gcn1: X=A -> H=B, Out=C (bias + self-loop seeded); scatter adds real edges
  k_gcn_gemm<<<(n + 15) / 16, 256, 0, stream>>>(A, g1wsw, g1b, dinv, B, C, n, 0);
  k_scatter<<<((size_t)n * 64 + 255) / 256, 256, 0, stream>>>(B, C, src, dst, dinv, n);

  // gcn2: X=relu(C) -> H=A, Out=B
  k_gcn_gemm<<<(n + 15) / 16, 256, 0, stream>>>(C, g2wsw, g2b, dinv, A, B, n, 1);
  k_scatter<<<((size_t)n * 64 + 255) / 256, 256, 0, stream>>>(A, B, src, dst, dinv, n);

  k_pool<<<256, 256, 0, stream>>>(B, src, batch, pooled, n);
  k_mlp<<<64, 256, 0, stream>>>(pooled, f1w, f1b, f2w, f2b, (float*)d_out);
}

// Round 4
// 1323.972 us; speedup vs baseline: 1.0101x; 1.0101x over previous
//
#include <hip/hip_runtime.h>

typedef unsigned int u32;
typedef unsigned short u16;
typedef short short8 __attribute__((ext_vector_type(8)));   // 8 x bf16 (4 VGPRs)
typedef float floatx4 __attribute__((ext_vector_type(4)));  // MFMA accumulator

static __device__ __forceinline__ u32 f2bf(float f) {
  u32 u = __float_as_uint(f);
  return (u + 0x7fffu + ((u >> 16) & 1u)) >> 16;  // RNE bf16 bits
}
// HW packed f32->bf16 (RNE), 1 instr replaces ~9 ALU ops of f2bf|f2bf<<16
static __device__ __forceinline__ u32 cvtpk(float lo, float hi) {
  u32 r;
  asm("v_cvt_pk_bf16_f32 %0, %1, %2" : "=v"(r) : "v"(lo), "v"(hi));
  return r;
}

// ---------------------------------------------------------------------------
// MFMA conventions (verified): for mfma_f32_16x16x32_bf16(A,B,C):
//   A-frag: lane holds A[m = lane&15][k = quad*8+j], j=0..7 (one 16B load)
//   B-frag: lane holds B[k = quad*8+j][n = lane&15]  (value = W[n][k])
//   C/D   : col(n) = lane&15, row(m) = quad*4 + reg
// conv1: A=weights(m=cout), B=x0T(n=p), K=64 (k=tap*8+cin; tap>4,cin>5 zero)
// conv2: A=x1t(m=p),  B=weights(n=o), K=96 (k=tap*16+c; tap>4 zero)
// fc:    A=sF frag,   B=fcwsw(n=outch), K=4096 (feat=o*128+p; p>119 zero)
//
// Round-r structure (r=0..3): fc K-dim split by p-pairs pt in {2r,2r+1}.
// conv2 output of round r lives in LDS sF (32 KiB, frag order, swizzled).
// conv1 recomputed per round over window pt' = 2r-1 .. 2r+2 (clamped 0..7);
// x1 window rows: lrow = globalrow - 32r + 16, rows 0..65, reads 16..52.
// Zero-trim: only lrows {16,17}@r=0 and {42..52}@r=3 are read-never-written.
// NOTE (R2 post-mortem): cross-tile ea prefetch + fc B-reg-prefetch REGRESSED
// (FETCH x2.6, dur +37%) — do not reintroduce. This is the R1 structure
// (best measured: 516 us) + T5 setprio around the fc MFMA cluster.
// LDS: sX0 34816 + sX1 12672 + sF 32768 = 80256 B -> 2 blocks/CU.
// ---------------------------------------------------------------------------

#define X0_ROWS 136    // u16[8] granules per node; row r = position r-2
#define X1W_ROWS 66    // sliding window rows (local)
#define X1W_LDA 24     // u16 per row (48 B, 16B-aligned rows)

__global__ __launch_bounds__(256, 2) void k_convfc(
    const float* __restrict__ ea,
    const u32* __restrict__ w1sw, const float* __restrict__ b1,
    const u32* __restrict__ w2sw, const float* __restrict__ b2,
    const u32* __restrict__ fcwsw, const float* __restrict__ fcb,
    float* __restrict__ xfc, int n, int ntiles)
{
  __shared__ __align__(16) u16 sX0[16][X0_ROWS * 8];        // 34816 B, all 16 nodes
  __shared__ __align__(16) u16 sX1[4][X1W_ROWS * X1W_LDA];  // 12672 B, per-wave window
  __shared__ __align__(16) u16 sF[32 * 64 * 8];             // 32768 B, fc A-frags

  const int t = threadIdx.x, lane = t & 63, wv = t >> 6;
  const int quad = lane >> 4, lr = lane & 15;

  // zero x0 once: halo rows (0,1) and pad rows (>=122) stay zero forever
  for (int i = t; i < 16 * X0_ROWS * 4; i += 256) ((u32*)sX0)[i] = 0;

  // weights into registers
  short8 w1f[2], w2f[2][3];
#pragma unroll
  for (int kb = 0; kb < 2; ++kb) w1f[kb] = ((const short8*)w1sw)[kb * 64 + lane];
#pragma unroll
  for (int ot = 0; ot < 2; ++ot)
#pragma unroll
    for (int kb = 0; kb < 3; ++kb)
      w2f[ot][kb] = ((const short8*)w2sw)[(ot * 3 + kb) * 64 + lane];

  float b1r[4];
#pragma unroll
  for (int r = 0; r < 4; ++r) b1r[r] = b1[quad * 4 + r];
  const float bv20 = b2[lr], bv21 = b2[16 + lr];

  // fc setup
  const int c0 = wv * 16 + lr, c1 = (wv + 4) * 16 + lr;
  const float bv0 = fcb[c0], bv1 = fcb[c1];
  const short8* bw = (const short8*)fcwsw;
  const short8* b0p = bw + ((size_t)wv * 128) * 64 + lane;
  const short8* b1p = bw + ((size_t)(wv + 4) * 128) * 64 + lane;
  const int j2base = wv * 4;

  __syncthreads();  // sX0 zero-init visible

  for (int tile = blockIdx.x; tile < ntiles; tile += gridDim.x) {
    const long node0 = (long)tile * 16;

    // ---- cooperative stage: ea -> sX0, one 16B row per thread-step --------
    // idx = nd*128 + p; 6 coalesced dword loads (stride 480B across channels),
    // one conflict-free ds_write_b128 per row. Rows p+2, p=0..119.
#pragma unroll
    for (int it = 0; it < 8; ++it) {
      int idx = t + it * 256;                 // 0..2047
      int nd = idx >> 7, p = idx & 127;
      if (p < 120) {
        long gn = node0 + nd;
        float v0 = 0.f, v1 = 0.f, v2 = 0.f, v3 = 0.f, v4 = 0.f, v5 = 0.f;
        if (gn < n) {
          const float* base = ea + (size_t)gn * 720 + p;
          v0 = base[0];   v1 = base[120]; v2 = base[240];
          v3 = base[360]; v4 = base[480]; v5 = base[600];
        }
        u32 w0 = cvtpk(v0, v1), w1 = cvtpk(v2, v3), w2 = cvtpk(v4, v5);
        *(uint4*)&sX0[nd][(p + 2) * 8] = make_uint4(w0, w1, w2, 0u);
      }
    }
    __syncthreads();

    floatx4 acc0 = {bv0, bv0, bv0, bv0};
    floatx4 acc1 = {bv1, bv1, bv1, bv1};

#pragma unroll
    for (int r = 0; r < 4; ++r) {
      u16* x1 = sX1[wv];
      // per-round zero-trim (wave-private buffer, no barrier needed)
      if (r == 0) {
        if (lane < 24) ((u32*)(x1 + 16 * X1W_LDA))[lane] = 0;   // lrows 16,17
      } else if (r == 3) {
        u32* z = (u32*)(x1 + 42 * X1W_LDA);                     // lrows 42..52
#pragma unroll
        for (int i2 = 0; i2 < 3; ++i2) {
          int i = lane + i2 * 64;
          if (i < 132) z[i] = 0;
        }
      }
#pragma unroll 1
      for (int jj = 0; jj < 4; ++jj) {
        const int j2 = j2base + jj;
        const u16* x0n = sX0[j2];
        // ---- conv1 over window pt' = 2r-1 .. 2r+2 (statically clamped) ----
#pragma unroll
        for (int q4 = 0; q4 < 4; ++q4) {
          const int ptp = 2 * r - 1 + q4;
          if (ptp >= 0 && ptp <= 7) {       // folds at compile time (r unrolled)
            const int row0 = ptp * 16 + lr;
            short8 bx0 = *(const short8*)&x0n[(row0 + quad) * 8];       // taps 0..3
            short8 bx1 = *(const short8*)&x0n[(row0 + 4 + quad) * 8];   // taps 4..7
            floatx4 a1 = {b1r[0], b1r[1], b1r[2], b1r[3]};
            a1 = __builtin_amdgcn_mfma_f32_16x16x32_bf16(w1f[0], bx0, a1, 0, 0, 0);
            a1 = __builtin_amdgcn_mfma_f32_16x16x32_bf16(w1f[1], bx1, a1, 0, 0, 0);
            if (ptp < 7 || lr < 8) {        // only valid positions p<120
              const int lrow = row0 + 18 - 32 * r;   // globalrow+2 -> window
              u32 lo = cvtpk(fmaxf(a1[0], 0.0f), fmaxf(a1[1], 0.0f));
              u32 hi = cvtpk(fmaxf(a1[2], 0.0f), fmaxf(a1[3], 0.0f));
              *(uint2*)&x1[lrow * X1W_LDA + quad * 4] = make_uint2(lo, hi);
            }
          }
        }
        // ---- conv2 for pt in {2r, 2r+1} -> sF (LDS, frag order, swizzled) ----
        const int tq = quad >> 1, cq = (quad & 1) * 8;
#pragma unroll
        for (int ptl = 0; ptl < 2; ++ptl) {
          const int lrow0 = ptl * 16 + lr + 16;
          short8 ax0 = *(const short8*)&x1[(lrow0 + tq) * X1W_LDA + cq];       // taps 0,1
          short8 ax1 = *(const short8*)&x1[(lrow0 + 2 + tq) * X1W_LDA + cq];   // taps 2,3
          short8 ax2 = *(const short8*)&x1[(lrow0 + 4 + tq) * X1W_LDA + cq];   // taps 4,5(zeroW)
#pragma unroll
          for (int ot = 0; ot < 2; ++ot) {
            const float bb = ot ? bv21 : bv20;
            floatx4 a2 = {bb, bb, bb, bb};
            a2 = __builtin_amdgcn_mfma_f32_16x16x32_bf16(ax0, w2f[ot][0], a2, 0, 0, 0);
            a2 = __builtin_amdgcn_mfma_f32_16x16x32_bf16(ax1, w2f[ot][1], a2, 0, 0, 0);
            a2 = __builtin_amdgcn_mfma_f32_16x16x32_bf16(ax2, w2f[ot][2], a2, 0, 0, 0);
            u32 lo = cvtpk(fmaxf(a2[0], 0.0f), fmaxf(a2[1], 0.0f));
            u32 hi = cvtpk(fmaxf(a2[2], 0.0f), fmaxf(a2[3], 0.0f));
            // value (node j2, o=ot*16+lr, p=pt*16+quad*4+rr)
            const int o = ot * 16 + lr;
            const int s = (ptl * 2 + tq) * 16 + j2;
            const int G = o * 64 + (s ^ (o & 7));   // bank swizzle
            *(uint2*)&sF[G * 8 + (quad & 1) * 4] = make_uint2(lo, hi);
          }
        }
      }  // jj
      __syncthreads();  // sF complete for this round

      // ---- fc partial: accumulate chunks o=0..31 of round r (ks = o*4+r) ----
      __builtin_amdgcn_s_setprio(1);
#pragma unroll 8
      for (int o = 0; o < 32; ++o) {
        short8 a = *(const short8*)&sF[(o * 64 + (lane ^ (o & 7))) * 8];
        const int ks = o * 4 + r;
        short8 bb0 = b0p[(size_t)ks * 64];
        short8 bb1 = b1p[(size_t)ks * 64];
        acc0 = __builtin_amdgcn_mfma_f32_16x16x32_bf16(a, bb0, acc0, 0, 0, 0);
        acc1 = __builtin_amdgcn_mfma_f32_16x16x32_bf16(a, bb1, acc1, 0, 0, 0);
      }
      __builtin_amdgcn_s_setprio(0);
      __syncthreads();  // fc reads done before next round overwrites sF
    }  // r

#pragma unroll
    for (int rr = 0; rr < 4; ++rr) {
      long node = node0 + quad * 4 + rr;
      if (node < n) {
        xfc[node * 128 + c0] = acc0[rr];
        xfc[node * 128 + c1] = acc1[rr];
      }
    }
    // last round's post-fc barrier already ordered all sX0/sF reads
    // before the next tile's stage writes
  }
}

// ---------------------------------------------------------------------------
// Merged prep: fcwsw / g1wsw / g2wsw / w1sw / w2sw swizzles + dinv=1 + pooled=0
// ---------------------------------------------------------------------------
__global__ void k_prep(const float* __restrict__ fcw, const float* __restrict__ g1w,
                       const float* __restrict__ g2w, const float* __restrict__ w1,
                       const float* __restrict__ w2,
                       uint4* __restrict__ fcwsw, uint4* __restrict__ g1wsw,
                       uint4* __restrict__ g2wsw, uint4* __restrict__ w1sw,
                       uint4* __restrict__ w2sw,
                       float* __restrict__ dinv, float* __restrict__ pooled, int n)
{
  int gid = blockIdx.x * 256 + threadIdx.x;
  if (gid < 65536) {  // fcwsw: entry = (nt*128+ks)*64+lane, feat k = o*128+p
    int e = gid, lane = e & 63, t2 = e >> 6, ks = t2 & 127, nt = t2 >> 7;
    int col = nt * 16 + (lane & 15);
    int k0 = ks * 32 + ((lane >> 4) & 3) * 8;
    u32 pk[4];
#pragma unroll
    for (int h = 0; h < 4; ++h) {
      u32 v01[2];
#pragma unroll
      for (int g = 0; g < 2; ++g) {
        int k = k0 + h * 2 + g;
        int o = k >> 7, p = k & 127;
        float v = (p < 120) ? fcw[(size_t)col * 3840 + o * 120 + p] : 0.0f;
        v01[g] = f2bf(v);
      }
      pk[h] = v01[0] | (v01[1] << 16);
    }
    fcwsw[e] = make_uint4(pk[0], pk[1], pk[2], pk[3]);
    return;
  }
  gid -= 65536;
  if (gid < 4096) {  // g1wsw / g2wsw: entry = (nt*4+kb)*64+lane
    const float* gw = (gid < 2048) ? g1w : g2w;
    uint4* out = (gid < 2048) ? g1wsw : g2wsw;
    int e = gid & 2047, lane = e & 63;
    int col = (e >> 8) * 16 + (lane & 15);            // nt = e>>8 (t2>>2)
    int k0 = ((e >> 6) & 3) * 32 + ((lane >> 4) & 3) * 8;
    u32 pk[4];
#pragma unroll
    for (int h = 0; h < 4; ++h)
      pk[h] = f2bf(gw[(size_t)col * 128 + k0 + h * 2]) |
              (f2bf(gw[(size_t)col * 128 + k0 + h * 2 + 1]) << 16);
    out[e] = make_uint4(pk[0], pk[1], pk[2], pk[3]);
    return;
  }
  gid -= 4096;
  if (gid < 128) {  // w1sw: entry = kb*64+lane; k = tap*8+cin
    int e = gid, lane = e & 63, kb = e >> 6, cout = lane & 15;
    int k0 = kb * 32 + ((lane >> 4) & 3) * 8;
    u32 pk[4];
#pragma unroll
    for (int h = 0; h < 4; ++h) {
      u32 v01[2];
#pragma unroll
      for (int g = 0; g < 2; ++g) {
        int k = k0 + h * 2 + g, tap = k >> 3, cin = k & 7;
        float v = (tap < 5 && cin < 6) ? w1[cout * 30 + cin * 5 + tap] : 0.0f;
        v01[g] = f2bf(v);
      }
      pk[h] = v01[0] | (v01[1] << 16);
    }
    w1sw[e] = make_uint4(pk[0], pk[1], pk[2], pk[3]);
    return;
  }
  gid -= 128;
  if (gid < 384) {  // w2sw: entry = (ot*3+kb)*64+lane; k = tap*16+c
    int e = gid, lane = e & 63, t2 = e >> 6;
    int kb = t2 % 3, ot = t2 / 3;
    int o = ot * 16 + (lane & 15);
    int k0 = kb * 32 + ((lane >> 4) & 3) * 8;
    u32 pk[4];
#pragma unroll
    for (int h = 0; h < 4; ++h) {
      u32 v01[2];
#pragma unroll
      for (int g = 0; g < 2; ++g) {
        int k = k0 + h * 2 + g, tap = k >> 4, c = k & 15;
        float v = (tap < 5) ? w2[o * 80 + c * 5 + tap] : 0.0f;
        v01[g] = f2bf(v);
      }
      pk[h] = v01[0] | (v01[1] << 16);
    }
    w2sw[e] = make_uint4(pk[0], pk[1], pk[2], pk[3]);
    return;
  }
  gid -= 384;
  if (gid < n) { dinv[gid] = 1.0f; return; }
  gid -= n;
  if (gid < 8192) pooled[gid] = 0.0f;
}

// ---------------------------------------------------------------------------
// GCN dense layer via MFMA, fused self-loop + bias:
//   H[i][o] = dinv[i] * sum_k act(X[i][k]) * W[o][k]   (pre-scaled for scatter)
//   Out[i][o] = bias[o] + dinv[i]^2 * sum_k act(X[i][k]) * W[o][k]
// ---------------------------------------------------------------------------
__global__ __launch_bounds__(256) void k_gcn_gemm(
    const float* __restrict__ X, const u32* __restrict__ wsw,
    const float* __restrict__ bias, const float* __restrict__ dinv,
    float* __restrict__ H, float* __restrict__ Out, int n, int relu)
{
  __shared__ __align__(16) u16 sA[16 * 136];
  __shared__ float sDi[16];
  const int t = threadIdx.x;
  const long node0 = (long)blockIdx.x * 16;
  {
    int nd = t >> 4, k0 = (t & 15) * 8;
    long node = node0 + nd;
    float v[8];
    if (node < n) {
      float4 f0 = *(const float4*)&X[node * 128 + k0];
      float4 f1 = *(const float4*)&X[node * 128 + k0 + 4];
      v[0]=f0.x; v[1]=f0.y; v[2]=f0.z; v[3]=f0.w; v[4]=f1.x; v[5]=f1.y; v[6]=f1.z; v[7]=f1.w;
      if (relu) {
#pragma unroll
        for (int i = 0; i < 8; ++i) v[i] = fmaxf(v[i], 0.0f);
      }
    } else {
#pragma unroll
      for (int i = 0; i < 8; ++i) v[i] = 0.0f;
    }
    u32 pk[4];
#pragma unroll
    for (int h = 0; h < 4; ++h) pk[h] = cvtpk(v[2*h], v[2*h+1]);
    *(uint4*)&sA[nd * 136 + k0] = make_uint4(pk[0], pk[1], pk[2], pk[3]);
    if (t < 16) sDi[t] = (node0 + t < n) ? dinv[node0 + t] : 0.0f;
  }
  __syncthreads();
  const int lane = t & 63, wv = t >> 6, quad = lane >> 4, lr = lane & 15;
  short8 af[4];
#pragma unroll
  for (int kb = 0; kb < 4; ++kb)
    af[kb] = *(const short8*)&sA[lr * 136 + kb * 32 + quad * 8];
#pragma unroll
  for (int h = 0; h < 2; ++h) {
    const int nt = wv + h * 4;
    const short8* bp = ((const short8*)wsw) + (nt * 4) * 64 + lane;
    floatx4 acc = {0.0f, 0.0f, 0.0f, 0.0f};
#pragma unroll
    for (int kb = 0; kb < 4; ++kb)
      acc = __builtin_amdgcn_mfma_f32_16x16x32_bf16(af[kb], bp[kb * 64], acc, 0, 0, 0);
    const int col = nt * 16 + lr;
    const float bcol = bias[col];
#pragma unroll
    for (int r = 0; r < 4; ++r) {
      long node = node0 + quad * 4 + r;
      if (node < n) {
        float hv = acc[r];
        float di = sDi[quad * 4 + r];
        H[node * 128 + col] = hv * di;            // pre-scaled by dinv[src]
        Out[node * 128 + col] = bcol + di * di * hv;
      }
    }
  }
}

// Two edges per wave (32 lanes x float4 each); Hs pre-scaled by dinv[src],
// so the message is Hs[s] * dinv[d]. Self-loops pre-seeded in Out.
__global__ void k_scatter(const float* __restrict__ Hs, float* __restrict__ Out,
                          const int* __restrict__ src, const int* __restrict__ dst,
                          const float* __restrict__ dinv, int n)
{
  const int gid = blockIdx.x * blockDim.x + threadIdx.x;
  const int e = gid >> 5;            // edge index (2 per wave)
  const int l = gid & 31;            // lane within edge: 32 x 16B = 512B row
  if (e >= n) return;
  const int s = src[e], d = dst[e];
  const float nrm = dinv[d];
  const float4 v = ((const float4*)(Hs + (size_t)s * 128))[l];
  float* o = Out + (size_t)d * 128 + l * 4;
  unsafeAtomicAdd(o + 0, v.x * nrm);
  unsafeAtomicAdd(o + 1, v.y * nrm);
  unsafeAtomicAdd(o + 2, v.z * nrm);
  unsafeAtomicAdd(o + 3, v.w * nrm);
}

__global__ void k_deg(float* dinv, const int* __restrict__ dst, int n) {
  int i = blockIdx.x * 256 + threadIdx.x; if (i < n) unsafeAtomicAdd(&dinv[dst[i]], 1.0f);
}
__global__ void k_rsqrt(float* p, int n) {
  int i = blockIdx.x * 256 + threadIdx.x; if (i < n) p[i] = rsqrtf(p[i]);
}

// LDS-staged pooling: pooled[batch[src[e]]] += X[e]
__global__ __launch_bounds__(256) void k_pool(const float* __restrict__ X,
    const int* __restrict__ src, const int* __restrict__ batch,
    float* __restrict__ pooled, int n)
{
  __shared__ float sAcc[64 * 128];
  for (int i = threadIdx.x; i < 8192; i += 256) sAcc[i] = 0.0f;
  __syncthreads();
  const int c = threadIdx.x & 127, half = threadIdx.x >> 7;
  for (int e = blockIdx.x * 2 + half; e < n; e += gridDim.x * 2) {
    int g = batch[src[e]];
    atomicAdd(&sAcc[g * 128 + c], X[(size_t)e * 128 + c]);
  }
  __syncthreads();
  for (int i = threadIdx.x; i < 8192; i += 256) unsafeAtomicAdd(&pooled[i], sAcc[i]);
}

// Final MLP head: relu(pooled @ fc1.T + b1) @ fc2.T + b2  (one block per graph)
__global__ __launch_bounds__(256) void k_mlp(const float* __restrict__ pooled,
    const float* __restrict__ f1w, const float* __restrict__ f1b,
    const float* __restrict__ f2w, const float* __restrict__ f2b,
    float* __restrict__ out)
{
  const int g = blockIdx.x, t = threadIdx.x;
  __shared__ float sP[128];
  __shared__ float sY[256];
  if (t < 128) sP[t] = pooled[g * 128 + t];
  __syncthreads();
  {
    const float* w = f1w + (size_t)t * 128;
    float a = f1b[t];
    for (int k = 0; k < 128; k += 4) {
      float4 w4 = *(const float4*)(w + k);
      a = fmaf(w4.x, sP[k], fmaf(w4.y, sP[k+1], fmaf(w4.z, sP[k+2], fmaf(w4.w, sP[k+3], a))));
    }
    sY[t] = fmaxf(a, 0.0f);
  }
  __syncthreads();
  if (t < 128) {
    const float* w = f2w + (size_t)t * 256;
    float a = f2b[t];
    for (int k = 0; k < 256; k += 4) {
      float4 w4 = *(const float4*)(w + k);
      a = fmaf(w4.x, sY[k], fmaf(w4.y, sY[k+1], fmaf(w4.z, sY[k+2], fmaf(w4.w, sY[k+3], a))));
    }
    out[g * 128 + t] = a;
  }
}

extern "C" void kernel_launch(void* const* d_in, const int* in_sizes, int n_in,
                              void* d_out, int out_size, void* d_ws, size_t ws_size,
                              hipStream_t stream) {
  const float* ea  = (const float*)d_in[0];
  const int* eidx  = (const int*)d_in[1];
  const int* batch = (const int*)d_in[2];
  const float* w1  = (const float*)d_in[4];
  const float* b1  = (const float*)d_in[5];
  const float* w2  = (const float*)d_in[6];
  const float* b2  = (const float*)d_in[7];
  const float* fcw = (const float*)d_in[8];
  const float* fcb = (const float*)d_in[9];
  const float* g1w = (const float*)d_in[10];
  const float* g1b = (const float*)d_in[11];
  const float* g2w = (const float*)d_in[12];
  const float* g2b = (const float*)d_in[13];
  const float* f1w = (const float*)d_in[14];
  const float* f1b = (const float*)d_in[15];
  const float* f2w = (const float*)d_in[16];
  const float* f2b = (const float*)d_in[17];

  const int n = in_sizes[0] / 720;   // 100000
  const int* src = eidx;             // edge_index[0]
  const int* dst = eidx + n;         // edge_index[1]

  // workspace layout (~155.3 MB; conv2->fc slab lives in LDS)
  float* A      = (float*)d_ws;                   // [n,128]
  float* B      = A + (size_t)n * 128;            // [n,128]
  float* C      = B + (size_t)n * 128;            // [n,128]
  float* dinv   = C + (size_t)n * 128;            // [n]
  float* pooled = dinv + n;                       // [64,128]
  u32*   fcwsw  = (u32*)(pooled + 64 * 128);      // 65536 uint4 = 1 MB
  u32*   g1wsw  = fcwsw + 65536 * 4;              // 2048 uint4
  u32*   g2wsw  = g1wsw + 2048 * 4;               // 2048 uint4
  u32*   w1sw   = g2wsw + 2048 * 4;               // 128 uint4
  u32*   w2sw   = w1sw + 128 * 4;                 // 384 uint4

  const int nb_n = (n + 255) / 256;
  const int ntiles = (n + 15) / 16;
  const int prep_total = 65536 + 2048 + 2048 + 128 + 384 + n + 8192;
  k_prep<<<(prep_total + 255) / 256, 256, 0, stream>>>(
      fcw, g1w, g2w, w1, w2, (uint4*)fcwsw, (uint4*)g1wsw, (uint4*)g2wsw,
      (uint4*)w1sw, (uint4*)w2sw, dinv, pooled, n);
  k_deg<<<nb_n, 256, 0, stream>>>(dinv, dst, n);
  k_rsqrt<<<nb_n, 256, 0, stream>>>(dinv, n);

  // 80.3 KiB LDS/block -> 2 blocks/CU; 512 blocks = 2 per CU exactly
  k_convfc<<<512, 256, 0, stream>>>(ea, w1sw, b1, w2sw, b2, fcwsw, fcb, A, n, ntiles);

  // gcn1: X=A -> H=B (pre-scaled), Out=C (bias + self-loop seeded)
  k_gcn_gemm<<<(n + 15) / 16, 256, 0, stream>>>(A, g1wsw, g1b, dinv, B, C, n, 0);
  k_scatter<<<((size_t)n * 32 + 255) / 256, 256, 0, stream>>>(B, C, src, dst, dinv, n);

  // gcn2: X=relu(C) -> H=A (pre-scaled), Out=B
  k_gcn_gemm<<<(n + 15) / 16, 256, 0, stream>>>(C, g2wsw, g2b, dinv, A, B, n, 1);
  k_scatter<<<((size_t)n * 32 + 255) / 256, 256, 0, stream>>>(A, B, src, dst, dinv, n);

  k_pool<<<256, 256, 0, stream>>>(B, src, batch, pooled, n);
  k_mlp<<<64, 256, 0, stream>>>(pooled, f1w, f1b, f2w, f2b, (float*)d_out);
}

// Round 5
// 1073.743 us; speedup vs baseline: 1.2455x; 1.2330x over previous
//
#include <hip/hip_runtime.h>

typedef unsigned int u32;
typedef unsigned short u16;
typedef short short8 __attribute__((ext_vector_type(8)));   // 8 x bf16 (4 VGPRs)
typedef float floatx4 __attribute__((ext_vector_type(4)));  // MFMA accumulator

static __device__ __forceinline__ u32 f2bf(float f) {
  u32 u = __float_as_uint(f);
  return (u + 0x7fffu + ((u >> 16) & 1u)) >> 16;  // RNE bf16 bits
}
// HW packed f32->bf16 (RNE); low 16 bits = first operand
static __device__ __forceinline__ u32 cvtpk(float lo, float hi) {
  u32 r;
  asm("v_cvt_pk_bf16_f32 %0, %1, %2" : "=v"(r) : "v"(lo), "v"(hi));
  return r;
}

// ---------------------------------------------------------------------------
// MFMA conventions (verified): for mfma_f32_16x16x32_bf16(A,B,C):
//   A-frag: lane holds A[m = lane&15][k = quad*8+j], j=0..7 (one 16B load)
//   B-frag: lane holds B[k = quad*8+j][n = lane&15]  (value = W[n][k])
//   C/D   : col(n) = lane&15, row(m) = quad*4 + reg
// conv1: A=weights(m=cout), B=x0T(n=p), K=64 (k=tap*8+cin; tap>4,cin>5 zero)
// conv2: A=x1t(m=p),  B=weights(n=o), K=96 (k=tap*16+c; tap>4 zero)
// fc:    A=sF frag,   B=fcwsw(n=outch), K=4096 (feat=o*128+p; p>119 zero)
// gcn1 (FUSED epilogue): xfc tile -> sT (LDS transpose) -> 8 MFMA with g1wsw
//   -> H1 (=B) and OutC seed (=C, bias + dinv^2*H1). Eliminates the xfc
//   round-trip (102 MB) and the gemm1 launch.
//
// Round-r structure (r=0..3): fc K-dim split by p-pairs pt in {2r,2r+1}.
// conv2 output of round r lives in LDS sF (32 KiB, frag order, swizzled).
// conv1 recomputed per round over window pt' = 2r-1 .. 2r+2 (clamped 0..7).
// NOTE (R2 post-mortem): cross-tile ea prefetch + fc B-reg-prefetch REGRESSED
// (FETCH x2.6, dur +37%) — do not reintroduce.
// NOTE (R3 post-mortem): per-lane-divergent scatter REGRESSED (+200us tail);
// edge aggregation now uses CSR gather (no atomics), built once.
// LDS: sX0 34816 + sX1 12672 + sF 32768 + sDi 64 = 80320 B -> 2 blocks/CU.
// ---------------------------------------------------------------------------

#define X0_ROWS 136    // u16[8] granules per node; row r = position r-2
#define X1W_ROWS 66    // sliding window rows (local)
#define X1W_LDA 24     // u16 per row (48 B, 16B-aligned rows)

__global__ __launch_bounds__(256, 2) void k_convfc(
    const float* __restrict__ ea,
    const u32* __restrict__ w1sw, const float* __restrict__ b1,
    const u32* __restrict__ w2sw, const float* __restrict__ b2,
    const u32* __restrict__ fcwsw, const float* __restrict__ fcb,
    const u32* __restrict__ g1wsw, const float* __restrict__ g1b,
    const float* __restrict__ dinv,
    float* __restrict__ H1, float* __restrict__ OutC, int n, int ntiles)
{
  __shared__ __align__(16) u16 sX0[16][X0_ROWS * 8];        // 34816 B, all 16 nodes
  __shared__ __align__(16) u16 sX1[4][X1W_ROWS * X1W_LDA];  // 12672 B, per-wave window
  __shared__ __align__(16) u16 sF[32 * 64 * 8];             // 32768 B, fc A-frags
  __shared__ float sDi[16];

  const int t = threadIdx.x, lane = t & 63, wv = t >> 6;
  const int quad = lane >> 4, lr = lane & 15;

  // zero x0 once: halo rows (0,1) and pad rows (>=122) stay zero forever
  for (int i = t; i < 16 * X0_ROWS * 4; i += 256) ((u32*)sX0)[i] = 0;

  // weights into registers
  short8 w1f[2], w2f[2][3];
#pragma unroll
  for (int kb = 0; kb < 2; ++kb) w1f[kb] = ((const short8*)w1sw)[kb * 64 + lane];
#pragma unroll
  for (int ot = 0; ot < 2; ++ot)
#pragma unroll
    for (int kb = 0; kb < 3; ++kb)
      w2f[ot][kb] = ((const short8*)w2sw)[(ot * 3 + kb) * 64 + lane];

  float b1r[4];
#pragma unroll
  for (int r = 0; r < 4; ++r) b1r[r] = b1[quad * 4 + r];
  const float bv20 = b2[lr], bv21 = b2[16 + lr];

  // fc setup
  const int c0 = wv * 16 + lr, c1 = (wv + 4) * 16 + lr;
  const float bv0 = fcb[c0], bv1 = fcb[c1];
  const float gb0 = g1b[c0], gb1 = g1b[c1];
  const short8* bw = (const short8*)fcwsw;
  const short8* b0p = bw + ((size_t)wv * 128) * 64 + lane;
  const short8* b1p = bw + ((size_t)(wv + 4) * 128) * 64 + lane;
  const short8* gp0 = ((const short8*)g1wsw) + (wv * 4) * 64 + lane;
  const short8* gp1 = ((const short8*)g1wsw) + ((wv + 4) * 4) * 64 + lane;
  const int j2base = wv * 4;

  __syncthreads();  // sX0 zero-init visible

  for (int tile = blockIdx.x; tile < ntiles; tile += gridDim.x) {
    const long node0 = (long)tile * 16;

    // ---- cooperative stage: ea -> sX0, one 16B row per thread-step --------
#pragma unroll
    for (int it = 0; it < 8; ++it) {
      int idx = t + it * 256;                 // 0..2047
      int nd = idx >> 7, p = idx & 127;
      if (p < 120) {
        long gn = node0 + nd;
        float v0 = 0.f, v1 = 0.f, v2 = 0.f, v3 = 0.f, v4 = 0.f, v5 = 0.f;
        if (gn < n) {
          const float* base = ea + (size_t)gn * 720 + p;
          v0 = base[0];   v1 = base[120]; v2 = base[240];
          v3 = base[360]; v4 = base[480]; v5 = base[600];
        }
        u32 w0 = cvtpk(v0, v1), w1 = cvtpk(v2, v3), w2 = cvtpk(v4, v5);
        *(uint4*)&sX0[nd][(p + 2) * 8] = make_uint4(w0, w1, w2, 0u);
      }
    }
    __syncthreads();

    floatx4 acc0 = {bv0, bv0, bv0, bv0};
    floatx4 acc1 = {bv1, bv1, bv1, bv1};

#pragma unroll
    for (int r = 0; r < 4; ++r) {
      u16* x1 = sX1[wv];
      // per-round zero-trim (wave-private buffer, no barrier needed)
      if (r == 0) {
        if (lane < 24) ((u32*)(x1 + 16 * X1W_LDA))[lane] = 0;   // lrows 16,17
      } else if (r == 3) {
        u32* z = (u32*)(x1 + 42 * X1W_LDA);                     // lrows 42..52
#pragma unroll
        for (int i2 = 0; i2 < 3; ++i2) {
          int i = lane + i2 * 64;
          if (i < 132) z[i] = 0;
        }
      }
#pragma unroll 1
      for (int jj = 0; jj < 4; ++jj) {
        const int j2 = j2base + jj;
        const u16* x0n = sX0[j2];
        // ---- conv1 over window pt' = 2r-1 .. 2r+2 (statically clamped) ----
#pragma unroll
        for (int q4 = 0; q4 < 4; ++q4) {
          const int ptp = 2 * r - 1 + q4;
          if (ptp >= 0 && ptp <= 7) {       // folds at compile time (r unrolled)
            const int row0 = ptp * 16 + lr;
            short8 bx0 = *(const short8*)&x0n[(row0 + quad) * 8];       // taps 0..3
            short8 bx1 = *(const short8*)&x0n[(row0 + 4 + quad) * 8];   // taps 4..7
            floatx4 a1 = {b1r[0], b1r[1], b1r[2], b1r[3]};
            a1 = __builtin_amdgcn_mfma_f32_16x16x32_bf16(w1f[0], bx0, a1, 0, 0, 0);
            a1 = __builtin_amdgcn_mfma_f32_16x16x32_bf16(w1f[1], bx1, a1, 0, 0, 0);
            if (ptp < 7 || lr < 8) {        // only valid positions p<120
              const int lrow = row0 + 18 - 32 * r;   // globalrow+2 -> window
              u32 lo = cvtpk(fmaxf(a1[0], 0.0f), fmaxf(a1[1], 0.0f));
              u32 hi = cvtpk(fmaxf(a1[2], 0.0f), fmaxf(a1[3], 0.0f));
              *(uint2*)&x1[lrow * X1W_LDA + quad * 4] = make_uint2(lo, hi);
            }
          }
        }
        // ---- conv2 for pt in {2r, 2r+1} -> sF (LDS, frag order, swizzled) ----
        const int tq = quad >> 1, cq = (quad & 1) * 8;
#pragma unroll
        for (int ptl = 0; ptl < 2; ++ptl) {
          const int lrow0 = ptl * 16 + lr + 16;
          short8 ax0 = *(const short8*)&x1[(lrow0 + tq) * X1W_LDA + cq];       // taps 0,1
          short8 ax1 = *(const short8*)&x1[(lrow0 + 2 + tq) * X1W_LDA + cq];   // taps 2,3
          short8 ax2 = *(const short8*)&x1[(lrow0 + 4 + tq) * X1W_LDA + cq];   // taps 4,5(zeroW)
#pragma unroll
          for (int ot = 0; ot < 2; ++ot) {
            const float bb = ot ? bv21 : bv20;
            floatx4 a2 = {bb, bb, bb, bb};
            a2 = __builtin_amdgcn_mfma_f32_16x16x32_bf16(ax0, w2f[ot][0], a2, 0, 0, 0);
            a2 = __builtin_amdgcn_mfma_f32_16x16x32_bf16(ax1, w2f[ot][1], a2, 0, 0, 0);
            a2 = __builtin_amdgcn_mfma_f32_16x16x32_bf16(ax2, w2f[ot][2], a2, 0, 0, 0);
            u32 lo = cvtpk(fmaxf(a2[0], 0.0f), fmaxf(a2[1], 0.0f));
            u32 hi = cvtpk(fmaxf(a2[2], 0.0f), fmaxf(a2[3], 0.0f));
            const int o = ot * 16 + lr;
            const int s = (ptl * 2 + tq) * 16 + j2;
            const int G = o * 64 + (s ^ (o & 7));   // bank swizzle
            *(uint2*)&sF[G * 8 + (quad & 1) * 4] = make_uint2(lo, hi);
          }
        }
      }  // jj
      __syncthreads();  // sF complete for this round

      // ---- fc partial: accumulate chunks o=0..31 of round r (ks = o*4+r) ----
      __builtin_amdgcn_s_setprio(1);
#pragma unroll 8
      for (int o = 0; o < 32; ++o) {
        short8 a = *(const short8*)&sF[(o * 64 + (lane ^ (o & 7))) * 8];
        const int ks = o * 4 + r;
        short8 bb0 = b0p[(size_t)ks * 64];
        short8 bb1 = b1p[(size_t)ks * 64];
        acc0 = __builtin_amdgcn_mfma_f32_16x16x32_bf16(a, bb0, acc0, 0, 0, 0);
        acc1 = __builtin_amdgcn_mfma_f32_16x16x32_bf16(a, bb1, acc1, 0, 0, 0);
      }
      __builtin_amdgcn_s_setprio(0);
      __syncthreads();  // fc reads done before next round overwrites sF
    }  // r

    // ---- fused gcn1: xfc tile -> sT (in sF space) -> 8 MFMA -> H1, OutC ----
    {
      u16* sT = sF;   // [16][136] bf16, same layout as k_gcn_gemm's sA
      if (t < 16) sDi[t] = (node0 + t < n) ? dinv[node0 + t] : 0.0f;
#pragma unroll
      for (int rr = 0; rr < 4; ++rr) {
        const int nd = quad * 4 + rr;
        sT[nd * 136 + c0] = (u16)cvtpk(acc0[rr], acc0[rr]);
        sT[nd * 136 + c1] = (u16)cvtpk(acc1[rr], acc1[rr]);
      }
      __syncthreads();  // sT + sDi visible
      short8 af[4];
#pragma unroll
      for (int kb = 0; kb < 4; ++kb)
        af[kb] = *(const short8*)&sT[lr * 136 + kb * 32 + quad * 8];
      floatx4 h0 = {0.f, 0.f, 0.f, 0.f}, h1 = {0.f, 0.f, 0.f, 0.f};
#pragma unroll
      for (int kb = 0; kb < 4; ++kb) {
        h0 = __builtin_amdgcn_mfma_f32_16x16x32_bf16(af[kb], gp0[kb * 64], h0, 0, 0, 0);
        h1 = __builtin_amdgcn_mfma_f32_16x16x32_bf16(af[kb], gp1[kb * 64], h1, 0, 0, 0);
      }
#pragma unroll
      for (int rr = 0; rr < 4; ++rr) {
        long node = node0 + quad * 4 + rr;
        if (node < n) {
          float di = sDi[quad * 4 + rr];
          H1[node * 128 + c0] = h0[rr];
          H1[node * 128 + c1] = h1[rr];
          OutC[node * 128 + c0] = gb0 + di * di * h0[rr];
          OutC[node * 128 + c1] = gb1 + di * di * h1[rr];
        }
      }
    }
    // next tile's stage barrier drains each wave's sT reads before any wave
    // overwrites sF (stage only touches sX0; conv2 writes come after barrier)
  }
}

// ---------------------------------------------------------------------------
// Merged prep: weight swizzles + dinv=1 + pooled=0 + degi=0
// ---------------------------------------------------------------------------
__global__ void k_prep(const float* __restrict__ fcw, const float* __restrict__ g1w,
                       const float* __restrict__ g2w, const float* __restrict__ w1,
                       const float* __restrict__ w2,
                       uint4* __restrict__ fcwsw, uint4* __restrict__ g1wsw,
                       uint4* __restrict__ g2wsw, uint4* __restrict__ w1sw,
                       uint4* __restrict__ w2sw,
                       float* __restrict__ dinv, float* __restrict__ pooled,
                       int* __restrict__ degi, int n)
{
  int gid = blockIdx.x * 256 + threadIdx.x;
  if (gid < 65536) {  // fcwsw: entry = (nt*128+ks)*64+lane, feat k = o*128+p
    int e = gid, lane = e & 63, t2 = e >> 6, ks = t2 & 127, nt = t2 >> 7;
    int col = nt * 16 + (lane & 15);
    int k0 = ks * 32 + ((lane >> 4) & 3) * 8;
    u32 pk[4];
#pragma unroll
    for (int h = 0; h < 4; ++h) {
      u32 v01[2];
#pragma unroll
      for (int g = 0; g < 2; ++g) {
        int k = k0 + h * 2 + g;
        int o = k >> 7, p = k & 127;
        float v = (p < 120) ? fcw[(size_t)col * 3840 + o * 120 + p] : 0.0f;
        v01[g] = f2bf(v);
      }
      pk[h] = v01[0] | (v01[1] << 16);
    }
    fcwsw[e] = make_uint4(pk[0], pk[1], pk[2], pk[3]);
    return;
  }
  gid -= 65536;
  if (gid < 4096) {  // g1wsw / g2wsw: entry = (nt*4+kb)*64+lane
    const float* gw = (gid < 2048) ? g1w : g2w;
    uint4* out = (gid < 2048) ? g1wsw : g2wsw;
    int e = gid & 2047, lane = e & 63;
    int col = (e >> 8) * 16 + (lane & 15);
    int k0 = ((e >> 6) & 3) * 32 + ((lane >> 4) & 3) * 8;
    u32 pk[4];
#pragma unroll
    for (int h = 0; h < 4; ++h)
      pk[h] = f2bf(gw[(size_t)col * 128 + k0 + h * 2]) |
              (f2bf(gw[(size_t)col * 128 + k0 + h * 2 + 1]) << 16);
    out[e] = make_uint4(pk[0], pk[1], pk[2], pk[3]);
    return;
  }
  gid -= 4096;
  if (gid < 128) {  // w1sw: entry = kb*64+lane; k = tap*8+cin
    int e = gid, lane = e & 63, kb = e >> 6, cout = lane & 15;
    int k0 = kb * 32 + ((lane >> 4) & 3) * 8;
    u32 pk[4];
#pragma unroll
    for (int h = 0; h < 4; ++h) {
      u32 v01[2];
#pragma unroll
      for (int g = 0; g < 2; ++g) {
        int k = k0 + h * 2 + g, tap = k >> 3, cin = k & 7;
        float v = (tap < 5 && cin < 6) ? w1[cout * 30 + cin * 5 + tap] : 0.0f;
        v01[g] = f2bf(v);
      }
      pk[h] = v01[0] | (v01[1] << 16);
    }
    w1sw[e] = make_uint4(pk[0], pk[1], pk[2], pk[3]);
    return;
  }
  gid -= 128;
  if (gid < 384) {  // w2sw: entry = (ot*3+kb)*64+lane; k = tap*16+c
    int e = gid, lane = e & 63, t2 = e >> 6;
    int kb = t2 % 3, ot = t2 / 3;
    int o = ot * 16 + (lane & 15);
    int k0 = kb * 32 + ((lane >> 4) & 3) * 8;
    u32 pk[4];
#pragma unroll
    for (int h = 0; h < 4; ++h) {
      u32 v01[2];
#pragma unroll
      for (int g = 0; g < 2; ++g) {
        int k = k0 + h * 2 + g, tap = k >> 4, c = k & 15;
        float v = (tap < 5) ? w2[o * 80 + c * 5 + tap] : 0.0f;
        v01[g] = f2bf(v);
      }
      pk[h] = v01[0] | (v01[1] << 16);
    }
    w2sw[e] = make_uint4(pk[0], pk[1], pk[2], pk[3]);
    return;
  }
  gid -= 384;
  if (gid < n) { dinv[gid] = 1.0f; return; }
  gid -= n;
  if (gid < 8192) { pooled[gid] = 0.0f; return; }
  gid -= 8192;
  if (gid < n) degi[gid] = 0;
}

// degree: dinv (float, self-loop preseeded 1.0) + int histogram for CSR
__global__ void k_deg(float* dinv, int* __restrict__ degi,
                      const int* __restrict__ dst, int n) {
  int i = blockIdx.x * 256 + threadIdx.x;
  if (i < n) {
    int d = dst[i];
    unsafeAtomicAdd(&dinv[d], 1.0f);
    atomicAdd(&degi[d], 1);
  }
}
__global__ void k_rsqrt(float* p, int n) {
  int i = blockIdx.x * 256 + threadIdx.x; if (i < n) p[i] = rsqrtf(p[i]);
}

// ---- CSR build: hierarchical exclusive scan of degi + slot fill -----------
__global__ void k_scan1(const int* __restrict__ degi, int* __restrict__ bsum, int n) {
  __shared__ int s[256];
  int b = blockIdx.x, t = threadIdx.x, i = b * 256 + t;
  s[t] = (i < n) ? degi[i] : 0;
  __syncthreads();
  for (int o = 128; o > 0; o >>= 1) {
    if (t < o) s[t] += s[t + o];
    __syncthreads();
  }
  if (t == 0) bsum[b] = s[0];
}
__global__ void k_scan2(const int* __restrict__ bsum, int* __restrict__ boff,
                        int* __restrict__ off, int nb, int n) {
  __shared__ int s[512];
  int t = threadIdx.x;
  int v = (t < nb) ? bsum[t] : 0;
  s[t] = v;
  __syncthreads();
  for (int o = 1; o < 512; o <<= 1) {
    int x = (t >= o) ? s[t - o] : 0;
    __syncthreads();
    s[t] += x;
    __syncthreads();
  }
  if (t < nb) boff[t] = s[t] - v;          // exclusive
  if (t == 511) off[n] = s[511];           // total in-edges (== n here)
}
__global__ void k_scan3(const int* __restrict__ degi, const int* __restrict__ boff,
                        int* __restrict__ off, int* __restrict__ fillptr, int n) {
  __shared__ int s[256];
  int b = blockIdx.x, t = threadIdx.x, i = b * 256 + t;
  int v = (i < n) ? degi[i] : 0;
  s[t] = v;
  __syncthreads();
  for (int o = 1; o < 256; o <<= 1) {
    int x = (t >= o) ? s[t - o] : 0;
    __syncthreads();
    s[t] += x;
    __syncthreads();
  }
  if (i < n) {
    int e = boff[b] + s[t] - v;
    off[i] = e;
    fillptr[i] = e;
  }
}
__global__ void k_fill(const int* __restrict__ src, const int* __restrict__ dst,
                       int* __restrict__ fillptr, int* __restrict__ csr, int n) {
  int e = blockIdx.x * 256 + threadIdx.x;
  if (e < n) {
    int slot = atomicAdd(&fillptr[dst[e]], 1);
    csr[slot] = src[e];
  }
}

// ---------------------------------------------------------------------------
// GCN dense layer via MFMA, fused self-loop + bias (R1-exact form):
//   H[i][o] = sum_k act(X[i][k]) * W[o][k]
//   Out[i][o] = bias[o] + dinv[i]^2 * H[i][o]
// ---------------------------------------------------------------------------
__global__ __launch_bounds__(256) void k_gcn_gemm(
    const float* __restrict__ X, const u32* __restrict__ wsw,
    const float* __restrict__ bias, const float* __restrict__ dinv,
    float* __restrict__ H, float* __restrict__ Out, int n, int relu)
{
  __shared__ __align__(16) u16 sA[16 * 136];
  __shared__ float sDi[16];
  const int t = threadIdx.x;
  const long node0 = (long)blockIdx.x * 16;
  {
    int nd = t >> 4, k0 = (t & 15) * 8;
    long node = node0 + nd;
    float v[8];
    if (node < n) {
      float4 f0 = *(const float4*)&X[node * 128 + k0];
      float4 f1 = *(const float4*)&X[node * 128 + k0 + 4];
      v[0]=f0.x; v[1]=f0.y; v[2]=f0.z; v[3]=f0.w; v[4]=f1.x; v[5]=f1.y; v[6]=f1.z; v[7]=f1.w;
      if (relu) {
#pragma unroll
        for (int i = 0; i < 8; ++i) v[i] = fmaxf(v[i], 0.0f);
      }
    } else {
#pragma unroll
      for (int i = 0; i < 8; ++i) v[i] = 0.0f;
    }
    u32 pk[4];
#pragma unroll
    for (int h = 0; h < 4; ++h) pk[h] = cvtpk(v[2*h], v[2*h+1]);
    *(uint4*)&sA[nd * 136 + k0] = make_uint4(pk[0], pk[1], pk[2], pk[3]);
    if (t < 16) sDi[t] = (node0 + t < n) ? dinv[node0 + t] : 0.0f;
  }
  __syncthreads();
  const int lane = t & 63, wv = t >> 6, quad = lane >> 4, lr = lane & 15;
  short8 af[4];
#pragma unroll
  for (int kb = 0; kb < 4; ++kb)
    af[kb] = *(const short8*)&sA[lr * 136 + kb * 32 + quad * 8];
#pragma unroll
  for (int h = 0; h < 2; ++h) {
    const int nt = wv + h * 4;
    const short8* bp = ((const short8*)wsw) + (nt * 4) * 64 + lane;
    floatx4 acc = {0.0f, 0.0f, 0.0f, 0.0f};
#pragma unroll
    for (int kb = 0; kb < 4; ++kb)
      acc = __builtin_amdgcn_mfma_f32_16x16x32_bf16(af[kb], bp[kb * 64], acc, 0, 0, 0);
    const int col = nt * 16 + lr;
    const float bcol = bias[col];
#pragma unroll
    for (int r = 0; r < 4; ++r) {
      long node = node0 + quad * 4 + r;
      if (node < n) {
        float hv = acc[r];
        float di = sDi[quad * 4 + r];
        H[node * 128 + col] = hv;
        Out[node * 128 + col] = bcol + di * di * hv;
      }
    }
  }
}

// CSR gather (replaces atomic scatter): one wave per dst node, wave-uniform
// indices (scalar loads). Out[d] += sum_j H[csr[j]] * dinv[s]*dinv[d].
// Nodes with no in-edges skip the read-modify-write entirely.
__global__ __launch_bounds__(256) void k_gather(
    const float* __restrict__ H, float* __restrict__ Out,
    const int* __restrict__ off, const int* __restrict__ csr,
    const float* __restrict__ dinv, int n)
{
  const int gid = blockIdx.x * blockDim.x + threadIdx.x;
  const int d = gid >> 6;
  const int lane = gid & 63;
  if (d >= n) return;
  const int j0 = off[d], j1 = off[d + 1];
  if (j0 == j1) return;
  const float dd = dinv[d];
  float2 acc = *(const float2*)(Out + (size_t)d * 128 + lane * 2);
  for (int j = j0; j < j1; ++j) {
    const int s = csr[j];
    const float nrm = dinv[s] * dd;
    const float2 v = *(const float2*)(H + (size_t)s * 128 + lane * 2);
    acc.x = fmaf(v.x, nrm, acc.x);
    acc.y = fmaf(v.y, nrm, acc.y);
  }
  *(float2*)(Out + (size_t)d * 128 + lane * 2) = acc;
}

// LDS-staged pooling: pooled[batch[src[e]]] += X[e]
__global__ __launch_bounds__(256) void k_pool(const float* __restrict__ X,
    const int* __restrict__ src, const int* __restrict__ batch,
    float* __restrict__ pooled, int n)
{
  __shared__ float sAcc[64 * 128];
  for (int i = threadIdx.x; i < 8192; i += 256) sAcc[i] = 0.0f;
  __syncthreads();
  const int c = threadIdx.x & 127, half = threadIdx.x >> 7;
  for (int e = blockIdx.x * 2 + half; e < n; e += gridDim.x * 2) {
    int g = batch[src[e]];
    atomicAdd(&sAcc[g * 128 + c], X[(size_t)e * 128 + c]);
  }
  __syncthreads();
  for (int i = threadIdx.x; i < 8192; i += 256) unsafeAtomicAdd(&pooled[i], sAcc[i]);
}

// Final MLP head: relu(pooled @ fc1.T + b1) @ fc2.T + b2  (one block per graph)
__global__ __launch_bounds__(256) void k_mlp(const float* __restrict__ pooled,
    const float* __restrict__ f1w, const float* __restrict__ f1b,
    const float* __restrict__ f2w, const float* __restrict__ f2b,
    float* __restrict__ out)
{
  const int g = blockIdx.x, t = threadIdx.x;
  __shared__ float sP[128];
  __shared__ float sY[256];
  if (t < 128) sP[t] = pooled[g * 128 + t];
  __syncthreads();
  {
    const float* w = f1w + (size_t)t * 128;
    float a = f1b[t];
    for (int k = 0; k < 128; k += 4) {
      float4 w4 = *(const float4*)(w + k);
      a = fmaf(w4.x, sP[k], fmaf(w4.y, sP[k+1], fmaf(w4.z, sP[k+2], fmaf(w4.w, sP[k+3], a))));
    }
    sY[t] = fmaxf(a, 0.0f);
  }
  __syncthreads();
  if (t < 128) {
    const float* w = f2w + (size_t)t * 256;
    float a = f2b[t];
    for (int k = 0; k < 256; k += 4) {
      float4 w4 = *(const float4*)(w + k);
      a = fmaf(w4.x, sY[k], fmaf(w4.y, sY[k+1], fmaf(w4.z, sY[k+2], fmaf(w4.w, sY[k+3], a))));
    }
    out[g * 128 + t] = a;
  }
}

extern "C" void kernel_launch(void* const* d_in, const int* in_sizes, int n_in,
                              void* d_out, int out_size, void* d_ws, size_t ws_size,
                              hipStream_t stream) {
  const float* ea  = (const float*)d_in[0];
  const int* eidx  = (const int*)d_in[1];
  const int* batch = (const int*)d_in[2];
  const float* w1  = (const float*)d_in[4];
  const float* b1  = (const float*)d_in[5];
  const float* w2  = (const float*)d_in[6];
  const float* b2  = (const float*)d_in[7];
  const float* fcw = (const float*)d_in[8];
  const float* fcb = (const float*)d_in[9];
  const float* g1w = (const float*)d_in[10];
  const float* g1b = (const float*)d_in[11];
  const float* g2w = (const float*)d_in[12];
  const float* g2b = (const float*)d_in[13];
  const float* f1w = (const float*)d_in[14];
  const float* f1b = (const float*)d_in[15];
  const float* f2w = (const float*)d_in[16];
  const float* f2b = (const float*)d_in[17];

  const int n = in_sizes[0] / 720;   // 100000
  const int* src = eidx;             // edge_index[0]
  const int* dst = eidx + n;         // edge_index[1]

  // workspace layout (~156.2 MB)
  float* A      = (float*)d_ws;                   // [n,128] (H2; aliased ints early)
  float* B      = A + (size_t)n * 128;            // [n,128] (H1, then Out2)
  float* C      = B + (size_t)n * 128;            // [n,128] (Out1 seed -> gcn1 out)
  float* dinv   = C + (size_t)n * 128;            // [n]
  float* pooled = dinv + n;                       // [64,128]
  u32*   fcwsw  = (u32*)(pooled + 64 * 128);      // 65536 uint4 = 1 MB
  u32*   g1wsw  = fcwsw + 65536 * 4;              // 2048 uint4
  u32*   g2wsw  = g1wsw + 2048 * 4;               // 2048 uint4
  u32*   w1sw   = g2wsw + 2048 * 4;               // 128 uint4
  u32*   w2sw   = w1sw + 128 * 4;                 // 384 uint4
  int*   off    = (int*)(w2sw + 384 * 4);         // [n+1]
  int*   csr    = off + (n + 1);                  // [n]
  // CSR scratch aliases A (A is dead until k_gcn_gemm #2 writes H2):
  int*   degi    = (int*)A;                       // [n]
  int*   fillptr = degi + n;                      // [n]
  int*   bsum    = fillptr + n;                   // [512]
  int*   boff    = bsum + 512;                    // [512]

  const int nb_n = (n + 255) / 256;
  const int ntiles = (n + 15) / 16;
  const int prep_total = 65536 + 2048 + 2048 + 128 + 384 + n + 8192 + n;
  k_prep<<<(prep_total + 255) / 256, 256, 0, stream>>>(
      fcw, g1w, g2w, w1, w2, (uint4*)fcwsw, (uint4*)g1wsw, (uint4*)g2wsw,
      (uint4*)w1sw, (uint4*)w2sw, dinv, pooled, degi, n);
  k_deg<<<nb_n, 256, 0, stream>>>(dinv, degi, dst, n);
  k_rsqrt<<<nb_n, 256, 0, stream>>>(dinv, n);
  // CSR build (once; reused by both gather passes)
  k_scan1<<<nb_n, 256, 0, stream>>>(degi, bsum, n);
  k_scan2<<<1, 512, 0, stream>>>(bsum, boff, off, nb_n, n);
  k_scan3<<<nb_n, 256, 0, stream>>>(degi, boff, off, fillptr, n);
  k_fill<<<nb_n, 256, 0, stream>>>(src, dst, fillptr, csr, n);

  // conv1+conv2+fc+gcn1-gemm fused: writes H1->B, Out1 seed->C
  k_convfc<<<512, 256, 0, stream>>>(ea, w1sw, b1, w2sw, b2, fcwsw, fcb,
                                    g1wsw, g1b, dinv, B, C, n, ntiles);

  // gcn1 edge aggregation: C += gather(B)
  k_gather<<<(int)(((size_t)n * 64 + 255) / 256), 256, 0, stream>>>(B, C, off, csr, dinv, n);

  // gcn2: X=relu(C) -> H=A, Out=B (seeded)
  k_gcn_gemm<<<(n + 15) / 16, 256, 0, stream>>>(C, g2wsw, g2b, dinv, A, B, n, 1);
  k_gather<<<(int)(((size_t)n * 64 + 255) / 256), 256, 0, stream>>>(A, B, off, csr, dinv, n);

  k_pool<<<256, 256, 0, stream>>>(B, src, batch, pooled, n);
  k_mlp<<<64, 256, 0, stream>>>(pooled, f1w, f1b, f2w, f2b, (float*)d_out);
}